// Round 12
// baseline (131.252 us; speedup 1.0000x reference)
//
#include <hip/hip_runtime.h>

// Gaussian-kernel MMD loss, N=M=8192, D=2 — 2 plain launches:
//   sort (bucket x-sort + means + zero) -> main (3072 phase-strided blocks,
//   ballot-mask quad skip, done-counter finalize).
// loss = mean(k_bb) + mean(k_tt) - 2*mean(k_bt), k = exp(-||x-y||^2/(2 s^2))
// - Coords stored pre-scaled by exp(log_scale)*sqrt(inv2s2*log2e), x-sorted.
//   Cross-term centering shift applied to A rows at compute time.
// - Trans-issue-bound (wave64 v_exp_f32 ~30 cy, R8/R9 fit): only exp COUNT
//   matters. Pairs with scaled |dx| > sqrt(24) contribute < 2^-24 each
//   (dropped mass ~6e-8 << 4.7e-6 threshold).
// - Block = (term, row-tile of 256 sorted rows, col-phase): owns quads
//   q == phase (mod 32) spread over the whole sorted range -> phase blocks
//   of a row-tile have identical work (fixes R10's binary-tile imbalance).
// - R12 fixes vs R11: (1) launch_bounds (256,4) — R11's (256,8) 64-VGPR cap
//   likely spilled the fatter skip kernel; (2) survival decided ONCE per wave
//   via __ballot -> 32-bit mask; inner while loop visits survivors only (no
//   per-quad dependent LDS read + branch); (3) final kernel folded into main
//   via done counter (R4-proven reader-only pattern).

#define BLOCK    256
#define NT_CROSS 1024
#define NT_TOT   3072
#define NBUCK    512
#define BXMIN    (-64.0f)
#define BSCALE   4.0f
#define CUT      4.8989795f   // sqrt(24)
#define LOG2E    1.4426950408889634f

typedef float v2f __attribute__((ext_vector_type(2)));

__device__ __forceinline__ float fexp2(float x) {
    return __builtin_amdgcn_exp2f(x);
}

// ---------------- sort: bucket x-sort + means + zero slots/dctr ----------
__global__ __launch_bounds__(1024) void sort_kernel(
    const float* __restrict__ base, const float* __restrict__ target,
    const float* __restrict__ log_sigma, const float* __restrict__ log_scale,
    int N, int M,
    float* __restrict__ xsB, float* __restrict__ ysB, float* __restrict__ csB,
    float* __restrict__ xsT, float* __restrict__ ysT, float* __restrict__ csT,
    double* __restrict__ msum, double* __restrict__ slots,
    unsigned* __restrict__ dctr)
{
    __shared__ unsigned hist[NBUCK], pref[NBUCK], cnt[NBUCK];
    __shared__ double mred[16][2];
    const int tid = threadIdx.x;
    const bool isB = (blockIdx.x == 0);
    if (isB) {
        if (tid < 64) slots[tid] = 0.0;
        if (tid == 64) *dctr = 0u;
    }

    const float sigma = expf(log_sigma[0]);
    const float sq = sqrtf((0.5f / (sigma * sigma)) * LOG2E);
    const float f0 = expf(log_scale[0]) * sq;
    const float f1 = expf(log_scale[1]) * sq;

    const float2* src = (const float2*)(isB ? base : target);
    const int n = isB ? N : M;
    float* xs = isB ? xsB : xsT;
    float* ys = isB ? ysB : ysT;
    float* cs = isB ? csB : csT;

    for (int i = tid; i < NBUCK; i += 1024) { hist[i] = 0u; cnt[i] = 0u; }
    __syncthreads();

    double sx = 0.0, sy = 0.0;
    for (int i = tid; i < n; i += 1024) {
        float2 a = src[i];
        float x = a.x * f0, y = a.y * f1;
        sx += (double)x; sy += (double)y;
        int b = min(max((int)((x - BXMIN) * BSCALE), 0), NBUCK - 1);
        atomicAdd(&hist[b], 1u);
    }
    for (int off = 32; off; off >>= 1) {
        sx += __shfl_down(sx, off);
        sy += __shfl_down(sy, off);
    }
    if ((tid & 63) == 0) { mred[tid >> 6][0] = sx; mred[tid >> 6][1] = sy; }
    __syncthreads();
    if (tid == 0) {
        double ax = 0, ay = 0;
        for (int k = 0; k < 16; ++k) { ax += mred[k][0]; ay += mred[k][1]; }
        msum[2 * blockIdx.x] = ax; msum[2 * blockIdx.x + 1] = ay;
    }

    // exclusive bucket starts: wave 0 only, 8 buckets/lane + shuffle scan
    if (tid < 64) {
        unsigned loc[8], run = 0;
        const int b0 = tid * 8;
#pragma unroll
        for (int k = 0; k < 8; ++k) { loc[k] = run; run += hist[b0 + k]; }
        const unsigned tot = run;
        unsigned pre = tot;
        for (int off = 1; off < 64; off <<= 1) {
            unsigned nbr = __shfl_up(pre, off);
            if (tid >= off) pre += nbr;
        }
        pre -= tot;
#pragma unroll
        for (int k = 0; k < 8; ++k) pref[b0 + k] = pre + loc[k];
    }
    __syncthreads();

    for (int i = tid; i < n; i += 1024) {
        float2 a = src[i];
        float x = a.x * f0, y = a.y * f1;
        int b = min(max((int)((x - BXMIN) * BSCALE), 0), NBUCK - 1);
        unsigned pos = pref[b] + atomicAdd(&cnt[b], 1u);
        xs[pos] = x;
        ys[pos] = y;
        cs[pos] = -fmaf(x, x, y * y);
    }
}

// ---------------- main: 3072 phase-strided blocks, ballot skip ------------
__global__ __launch_bounds__(BLOCK, 4) void mmd_main(
    int N, int M,
    const float* __restrict__ xsB, const float* __restrict__ ysB,
    const float* __restrict__ csB,
    const float* __restrict__ xsT, const float* __restrict__ ysT,
    const float* __restrict__ csT,
    const double* __restrict__ msum, double* __restrict__ slots,
    unsigned* __restrict__ dctr, float* __restrict__ out)
{
    __shared__ __align__(16) float tbx[256];
    __shared__ __align__(16) float tby[256];
    __shared__ __align__(16) float tbc[256];
    __shared__ __align__(8)  float2 qb[64];
    __shared__ double wredd[4];
    __shared__ int lastf;

    const int tid = threadIdx.x;
    const int t   = blockIdx.x;

    const double wNN = 1.0 / ((double)N * (double)N);
    const double wMM = 1.0 / ((double)M * (double)M);
    const double wNM = -2.0 / ((double)N * (double)M);

    // ---- decode: (sym?, term, row-tile, phase) ----
    int rt, phase, term;
    bool sym;
    const float *xA, *yA, *xB, *yB, *cB;
    double wt;
    float shx = 0.f, shy = 0.f;
    if (t < NT_CROSS) {
        sym = false; term = 2;
        rt = t >> 5; phase = t & 31;
        xA = xsB; yA = ysB; xB = xsT; yB = ysT; cB = csT;
        wt = wNM;
        shx = (float)(msum[0] / (double)N - msum[2] / (double)M);
        shy = (float)(msum[1] / (double)N - msum[3] / (double)M);
    } else {
        sym = true;
        const int u = t - NT_CROSS;
        term = (u >= 1024) ? 1 : 0;
        const int v = u & 1023;
        rt = v >> 5; phase = v & 31;
        if (term) { xA = xsT; yA = ysT; xB = xsT; yB = ysT; cB = csT; }
        else      { xA = xsB; yA = ysB; xB = xsB; yB = ysB; cB = csB; }
        wt = 2.0 * (term ? wMM : wNN);
    }
    const int i0  = rt * 256;
    const int jq0 = 4 * phase;

    // ---- stage 64 strided quads (SoA) + per-quad x bounds ----
    {
        const int g = tid & 63;
        const int addr = jq0 + 128 * g;
        if (tid < 64) {
            float4 v4 = *(const float4*)(xB + addr);
            *(float4*)&tbx[4 * g] = v4;
            qb[g] = make_float2(fminf(fminf(v4.x, v4.y), fminf(v4.z, v4.w)),
                                fmaxf(fmaxf(v4.x, v4.y), fmaxf(v4.z, v4.w)));
        } else if (tid < 128) {
            *(float4*)&tby[4 * g] = *(const float4*)(yB + addr);
        } else if (tid < 192) {
            *(float4*)&tbc[4 * g] = *(const float4*)(cB + addr);
        }
    }
    __syncthreads();

    // ---- per-thread rows r0, r0+1 (wave = 128 consecutive sorted rows) ----
    const int u_    = tid & 127;
    const int r0    = i0 + 2 * u_;
    const int qoff  = (tid >> 7) * 32;
    const int wr_lo = i0 + ((tid >> 6) & 1) * 128;
    const int wr_hi = wr_lo + 127;

    float2 xr = *(const float2*)(xA + r0);
    float2 yr = *(const float2*)(yA + r0);
    const float axr0 = xr.x - shx, axr1 = xr.y - shx;
    const float ayr0 = yr.x - shy, ayr1 = yr.y - shy;
    const float ax2s[2] = { axr0 + axr0, axr1 + axr1 };
    const float ay2s[2] = { ayr0 + ayr0, ayr1 + ayr1 };
    const float A0s[2]  = { -fmaf(axr0, axr0, ayr0 * ayr0),
                            -fmaf(axr1, axr1, ayr1 * ayr1) };

    float rmin = fminf(axr0, axr1), rmax = fmaxf(axr0, axr1);
    for (int off = 32; off; off >>= 1) {
        rmin = fminf(rmin, __shfl_xor(rmin, off));
        rmax = fmaxf(rmax, __shfl_xor(rmax, off));
    }
    const float rminc = rmin - CUT, rmaxc = rmax + CUT;

    // ---- wave-uniform survival masks (one ballot, lanes 0-31 <-> quads) ----
    const int lm   = tid & 31;               // quad index within this half
    const int qlm  = qoff + lm;
    float2 qrm = qb[qlm];
    const bool xs_ok = !(qrm.x > rmaxc || qrm.y < rminc);
    unsigned fmask, bmask = 0u;
    if (!sym) {
        fmask = (unsigned)__ballot(xs_ok);
    } else {
        const int jqm = jq0 + 128 * qlm;
        const bool below = (jqm + 3) < wr_lo;
        const bool band  = !below && (jqm <= wr_hi);
        const bool fullq = !below && !band && xs_ok;
        fmask = (unsigned)__ballot(fullq);
        bmask = (unsigned)__ballot(band);
    }

    v2f s00 = {0.f, 0.f}, s01 = {0.f, 0.f};
    v2f s10 = {0.f, 0.f}, s11 = {0.f, 0.f};

    // ---- survivors-only loop (plain / weight-2 path) ----
    while (fmask) {
        const int m = __builtin_ctz(fmask);
        fmask &= fmask - 1;
        const int qi = qoff + m;
        float4 BX = *(const float4*)&tbx[4 * qi];
        float4 BY = *(const float4*)&tby[4 * qi];
        float4 C  = *(const float4*)&tbc[4 * qi];
        v2f bxa = { BX.x, BX.y }, bxb = { BX.z, BX.w };
        v2f bya = { BY.x, BY.y }, byb = { BY.z, BY.w };
        v2f ca  = { C.x,  C.y  }, cb  = { C.z,  C.w  };
        {
            v2f A0v = { A0s[0], A0s[0] };
            v2f axv = { ax2s[0], ax2s[0] };
            v2f ayv = { ay2s[0], ay2s[0] };
            v2f ea = axv * bxa + (ayv * bya + (ca + A0v));
            v2f eb = axv * bxb + (ayv * byb + (cb + A0v));
            s00 += (v2f){ fexp2(ea.x), fexp2(ea.y) };
            s01 += (v2f){ fexp2(eb.x), fexp2(eb.y) };
        }
        {
            v2f A0v = { A0s[1], A0s[1] };
            v2f axv = { ax2s[1], ax2s[1] };
            v2f ayv = { ay2s[1], ay2s[1] };
            v2f ea = axv * bxa + (ayv * bya + (ca + A0v));
            v2f eb = axv * bxb + (ayv * byb + (cb + A0v));
            s10 += (v2f){ fexp2(ea.x), fexp2(ea.y) };
            s11 += (v2f){ fexp2(eb.x), fexp2(eb.y) };
        }
    }

    // ---- diagonal-band quads (sym only, ~1-2 per wave): per-pair 2/1/0 ----
    float sge = 0.f, sgt = 0.f;
    while (bmask) {
        const int m = __builtin_ctz(bmask);
        bmask &= bmask - 1;
        const int qi = qoff + m;
        const int jq = jq0 + 128 * qi;
        float4 BX = *(const float4*)&tbx[4 * qi];
        float4 BY = *(const float4*)&tby[4 * qi];
        float4 C  = *(const float4*)&tbc[4 * qi];
#pragma unroll
        for (int k = 0; k < 2; ++k) {
            const int row = r0 + k;
            float e0 = fmaf(ax2s[k], BX.x, fmaf(ay2s[k], BY.x, C.x + A0s[k]));
            float e1 = fmaf(ax2s[k], BX.y, fmaf(ay2s[k], BY.y, C.y + A0s[k]));
            float e2 = fmaf(ax2s[k], BX.z, fmaf(ay2s[k], BY.z, C.z + A0s[k]));
            float e3 = fmaf(ax2s[k], BX.w, fmaf(ay2s[k], BY.w, C.w + A0s[k]));
            float v0 = fexp2(e0), v1 = fexp2(e1);
            float v2 = fexp2(e2), v3 = fexp2(e3);
            sge += (jq + 0 >= row) ? v0 : 0.f;  sgt += (jq + 0 > row) ? v0 : 0.f;
            sge += (jq + 1 >= row) ? v1 : 0.f;  sgt += (jq + 1 > row) ? v1 : 0.f;
            sge += (jq + 2 >= row) ? v2 : 0.f;  sgt += (jq + 2 > row) ? v2 : 0.f;
            sge += (jq + 3 >= row) ? v3 : 0.f;  sgt += (jq + 3 > row) ? v3 : 0.f;
        }
    }

    v2f st0 = s00 + s01, st1 = s10 + s11;
    double result = wt * ((double)(st0.x + st0.y) + (double)(st1.x + st1.y));
    if (sym) result += (term ? wMM : wNN) * (double)(sge + sgt);

    // ---- block reduce (f64), publish, done-counter finalize ----
    for (int off = 32; off; off >>= 1) result += __shfl_down(result, off);
    if ((tid & 63) == 0) wredd[tid >> 6] = result;
    __syncthreads();
    if (tid == 0) {
        double s = wredd[0] + wredd[1] + wredd[2] + wredd[3];
        atomicAdd(&slots[t & 63], s);
        __threadfence();
        unsigned d = atomicAdd(dctr, 1u);
        lastf = (d == (unsigned)(NT_TOT - 1)) ? 1 : 0;
    }
    __syncthreads();
    if (lastf) {
        __threadfence();
        double v = 0.0;
        if (tid < 64) v = atomicAdd(&slots[tid], 0.0);   // atomic read
        if (tid < 64) {
            for (int off = 32; off; off >>= 1) v += __shfl_down(v, off);
            if (tid == 0) out[0] = (float)v;
        }
    }
}

extern "C" void kernel_launch(void* const* d_in, const int* in_sizes, int n_in,
                              void* d_out, int out_size, void* d_ws, size_t ws_size,
                              hipStream_t stream)
{
    const float* base      = (const float*)d_in[0];
    const float* target    = (const float*)d_in[1];
    const float* log_sigma = (const float*)d_in[2];
    const float* log_scale = (const float*)d_in[3];
    float* out = (float*)d_out;

    int N = in_sizes[0] / 2;
    int M = in_sizes[1] / 2;

    char* ws = (char*)d_ws;
    double*   msum  = (double*)ws;               // 4 doubles
    double*   slots = (double*)(ws + 64);        // 64 doubles
    unsigned* dctr  = (unsigned*)(ws + 640);
    float*    arr   = (float*)(ws + 1024);
    float* xsB = arr;
    float* ysB = xsB + N;
    float* csB = ysB + N;
    float* xsT = csB + N;
    float* ysT = xsT + M;
    float* csT = ysT + M;

    sort_kernel<<<2, 1024, 0, stream>>>(base, target, log_sigma, log_scale,
                                        N, M, xsB, ysB, csB, xsT, ysT, csT,
                                        msum, slots, dctr);
    mmd_main<<<NT_TOT, BLOCK, 0, stream>>>(N, M, xsB, ysB, csB,
                                           xsT, ysT, csT, msum, slots,
                                           dctr, out);
}

// Round 13
// 94.719 us; speedup vs baseline: 1.3857x; 1.3857x over previous
//
#include <hip/hip_runtime.h>

// Gaussian-kernel MMD loss, N=M=8192, D=2 — 3 plain launches:
//   sort (bucket x-sort + means + zero) -> main (3072 phase-strided blocks,
//   ballot-mask quad skip) -> final (reduce 64 slots).
// loss = mean(k_bb) + mean(k_tt) - 2*mean(k_bt), k = exp(-||x-y||^2/(2 s^2))
// - Coords stored pre-scaled by exp(log_scale)*sqrt(inv2s2*log2e), x-sorted.
//   Cross-term centering shift applied to A rows at compute time.
// - Trans-issue-bound (wave64 v_exp_f32 ~30 cy, R8/R9 fit): only exp COUNT
//   matters. Pairs with scaled |dx| > sqrt(24) contribute < 2^-24 each
//   (dropped mass ~6e-8 << 4.7e-6 threshold).
// - Block = (term, row-tile of 256 sorted rows, col-phase): owns quads
//   q == phase (mod 32) spread over the whole sorted range -> phase blocks
//   of a row-tile have identical work (fixes R10's binary-tile imbalance).
// - Survival decided once per wave via __ballot -> 32-bit mask; inner while
//   loop visits survivors only.
// - R13 fix vs R12: NO same-address done-counter. R4/R5/R12 all show single-
//   address read-returning atomics with >=2k blocks cost ~60-125 us (L2
//   serialization); R6/R8 (64 spread slots + tiny final kernel) cost ~2 us.

#define BLOCK    256
#define NT_CROSS 1024
#define NT_TOT   3072
#define NBUCK    512
#define BXMIN    (-64.0f)
#define BSCALE   4.0f
#define CUT      4.8989795f   // sqrt(24)
#define LOG2E    1.4426950408889634f

typedef float v2f __attribute__((ext_vector_type(2)));

__device__ __forceinline__ float fexp2(float x) {
    return __builtin_amdgcn_exp2f(x);
}

// ---------------- sort: bucket x-sort + means + zero slots ----------
__global__ __launch_bounds__(1024) void sort_kernel(
    const float* __restrict__ base, const float* __restrict__ target,
    const float* __restrict__ log_sigma, const float* __restrict__ log_scale,
    int N, int M,
    float* __restrict__ xsB, float* __restrict__ ysB, float* __restrict__ csB,
    float* __restrict__ xsT, float* __restrict__ ysT, float* __restrict__ csT,
    double* __restrict__ msum, double* __restrict__ slots)
{
    __shared__ unsigned hist[NBUCK], pref[NBUCK], cnt[NBUCK];
    __shared__ double mred[16][2];
    const int tid = threadIdx.x;
    const bool isB = (blockIdx.x == 0);
    if (isB && tid < 64) slots[tid] = 0.0;

    const float sigma = expf(log_sigma[0]);
    const float sq = sqrtf((0.5f / (sigma * sigma)) * LOG2E);
    const float f0 = expf(log_scale[0]) * sq;
    const float f1 = expf(log_scale[1]) * sq;

    const float2* src = (const float2*)(isB ? base : target);
    const int n = isB ? N : M;
    float* xs = isB ? xsB : xsT;
    float* ys = isB ? ysB : ysT;
    float* cs = isB ? csB : csT;

    for (int i = tid; i < NBUCK; i += 1024) { hist[i] = 0u; cnt[i] = 0u; }
    __syncthreads();

    double sx = 0.0, sy = 0.0;
    for (int i = tid; i < n; i += 1024) {
        float2 a = src[i];
        float x = a.x * f0, y = a.y * f1;
        sx += (double)x; sy += (double)y;
        int b = min(max((int)((x - BXMIN) * BSCALE), 0), NBUCK - 1);
        atomicAdd(&hist[b], 1u);
    }
    for (int off = 32; off; off >>= 1) {
        sx += __shfl_down(sx, off);
        sy += __shfl_down(sy, off);
    }
    if ((tid & 63) == 0) { mred[tid >> 6][0] = sx; mred[tid >> 6][1] = sy; }
    __syncthreads();
    if (tid == 0) {
        double ax = 0, ay = 0;
        for (int k = 0; k < 16; ++k) { ax += mred[k][0]; ay += mred[k][1]; }
        msum[2 * blockIdx.x] = ax; msum[2 * blockIdx.x + 1] = ay;
    }

    // exclusive bucket starts: wave 0 only, 8 buckets/lane + shuffle scan
    if (tid < 64) {
        unsigned loc[8], run = 0;
        const int b0 = tid * 8;
#pragma unroll
        for (int k = 0; k < 8; ++k) { loc[k] = run; run += hist[b0 + k]; }
        const unsigned tot = run;
        unsigned pre = tot;
        for (int off = 1; off < 64; off <<= 1) {
            unsigned nbr = __shfl_up(pre, off);
            if (tid >= off) pre += nbr;
        }
        pre -= tot;
#pragma unroll
        for (int k = 0; k < 8; ++k) pref[b0 + k] = pre + loc[k];
    }
    __syncthreads();

    for (int i = tid; i < n; i += 1024) {
        float2 a = src[i];
        float x = a.x * f0, y = a.y * f1;
        int b = min(max((int)((x - BXMIN) * BSCALE), 0), NBUCK - 1);
        unsigned pos = pref[b] + atomicAdd(&cnt[b], 1u);
        xs[pos] = x;
        ys[pos] = y;
        cs[pos] = -fmaf(x, x, y * y);
    }
}

// ---------------- main: 3072 phase-strided blocks, ballot skip ------------
__global__ __launch_bounds__(BLOCK, 8) void mmd_main(
    int N, int M,
    const float* __restrict__ xsB, const float* __restrict__ ysB,
    const float* __restrict__ csB,
    const float* __restrict__ xsT, const float* __restrict__ ysT,
    const float* __restrict__ csT,
    const double* __restrict__ msum, double* __restrict__ slots)
{
    __shared__ __align__(16) float tbx[256];
    __shared__ __align__(16) float tby[256];
    __shared__ __align__(16) float tbc[256];
    __shared__ __align__(8)  float2 qb[64];
    __shared__ double wredd[4];

    const int tid = threadIdx.x;
    const int t   = blockIdx.x;

    const double wNN = 1.0 / ((double)N * (double)N);
    const double wMM = 1.0 / ((double)M * (double)M);
    const double wNM = -2.0 / ((double)N * (double)M);

    // ---- decode: (sym?, term, row-tile, phase) ----
    int rt, phase, term;
    bool sym;
    const float *xA, *yA, *xB, *yB, *cB;
    double wt;
    float shx = 0.f, shy = 0.f;
    if (t < NT_CROSS) {
        sym = false; term = 2;
        rt = t >> 5; phase = t & 31;
        xA = xsB; yA = ysB; xB = xsT; yB = ysT; cB = csT;
        wt = wNM;
        shx = (float)(msum[0] / (double)N - msum[2] / (double)M);
        shy = (float)(msum[1] / (double)N - msum[3] / (double)M);
    } else {
        sym = true;
        const int u = t - NT_CROSS;
        term = (u >= 1024) ? 1 : 0;
        const int v = u & 1023;
        rt = v >> 5; phase = v & 31;
        if (term) { xA = xsT; yA = ysT; xB = xsT; yB = ysT; cB = csT; }
        else      { xA = xsB; yA = ysB; xB = xsB; yB = ysB; cB = csB; }
        wt = 2.0 * (term ? wMM : wNN);
    }
    const int i0  = rt * 256;
    const int jq0 = 4 * phase;

    // ---- stage 64 strided quads (SoA) + per-quad x bounds ----
    {
        const int g = tid & 63;
        const int addr = jq0 + 128 * g;
        if (tid < 64) {
            float4 v4 = *(const float4*)(xB + addr);
            *(float4*)&tbx[4 * g] = v4;
            qb[g] = make_float2(fminf(fminf(v4.x, v4.y), fminf(v4.z, v4.w)),
                                fmaxf(fmaxf(v4.x, v4.y), fmaxf(v4.z, v4.w)));
        } else if (tid < 128) {
            *(float4*)&tby[4 * g] = *(const float4*)(yB + addr);
        } else if (tid < 192) {
            *(float4*)&tbc[4 * g] = *(const float4*)(cB + addr);
        }
    }
    __syncthreads();

    // ---- per-thread rows r0, r0+1 (wave = 128 consecutive sorted rows) ----
    const int u_    = tid & 127;
    const int r0    = i0 + 2 * u_;
    const int qoff  = (tid >> 7) * 32;
    const int wr_lo = i0 + ((tid >> 6) & 1) * 128;
    const int wr_hi = wr_lo + 127;

    float2 xr = *(const float2*)(xA + r0);
    float2 yr = *(const float2*)(yA + r0);
    const float axr0 = xr.x - shx, axr1 = xr.y - shx;
    const float ayr0 = yr.x - shy, ayr1 = yr.y - shy;
    const float ax2s[2] = { axr0 + axr0, axr1 + axr1 };
    const float ay2s[2] = { ayr0 + ayr0, ayr1 + ayr1 };
    const float A0s[2]  = { -fmaf(axr0, axr0, ayr0 * ayr0),
                            -fmaf(axr1, axr1, ayr1 * ayr1) };

    float rmin = fminf(axr0, axr1), rmax = fmaxf(axr0, axr1);
    for (int off = 32; off; off >>= 1) {
        rmin = fminf(rmin, __shfl_xor(rmin, off));
        rmax = fmaxf(rmax, __shfl_xor(rmax, off));
    }
    const float rminc = rmin - CUT, rmaxc = rmax + CUT;

    // ---- wave-uniform survival masks (one ballot, lanes 0-31 <-> quads) ----
    const int lm   = tid & 31;
    const int qlm  = qoff + lm;
    float2 qrm = qb[qlm];
    const bool xs_ok = !(qrm.x > rmaxc || qrm.y < rminc);
    unsigned fmask, bmask = 0u;
    if (!sym) {
        fmask = (unsigned)__ballot(xs_ok);
    } else {
        const int jqm = jq0 + 128 * qlm;
        const bool below = (jqm + 3) < wr_lo;
        const bool band  = !below && (jqm <= wr_hi);
        const bool fullq = !below && !band && xs_ok;
        fmask = (unsigned)__ballot(fullq);
        bmask = (unsigned)__ballot(band);
    }

    v2f s00 = {0.f, 0.f}, s01 = {0.f, 0.f};
    v2f s10 = {0.f, 0.f}, s11 = {0.f, 0.f};

    // ---- survivors-only loop (plain / weight-2 path) ----
    while (fmask) {
        const int m = __builtin_ctz(fmask);
        fmask &= fmask - 1;
        const int qi = qoff + m;
        float4 BX = *(const float4*)&tbx[4 * qi];
        float4 BY = *(const float4*)&tby[4 * qi];
        float4 C  = *(const float4*)&tbc[4 * qi];
        v2f bxa = { BX.x, BX.y }, bxb = { BX.z, BX.w };
        v2f bya = { BY.x, BY.y }, byb = { BY.z, BY.w };
        v2f ca  = { C.x,  C.y  }, cb  = { C.z,  C.w  };
        {
            v2f A0v = { A0s[0], A0s[0] };
            v2f axv = { ax2s[0], ax2s[0] };
            v2f ayv = { ay2s[0], ay2s[0] };
            v2f ea = axv * bxa + (ayv * bya + (ca + A0v));
            v2f eb = axv * bxb + (ayv * byb + (cb + A0v));
            s00 += (v2f){ fexp2(ea.x), fexp2(ea.y) };
            s01 += (v2f){ fexp2(eb.x), fexp2(eb.y) };
        }
        {
            v2f A0v = { A0s[1], A0s[1] };
            v2f axv = { ax2s[1], ax2s[1] };
            v2f ayv = { ay2s[1], ay2s[1] };
            v2f ea = axv * bxa + (ayv * bya + (ca + A0v));
            v2f eb = axv * bxb + (ayv * byb + (cb + A0v));
            s10 += (v2f){ fexp2(ea.x), fexp2(ea.y) };
            s11 += (v2f){ fexp2(eb.x), fexp2(eb.y) };
        }
    }

    // ---- diagonal-band quads (sym only, ~1-2 per wave): per-pair 2/1/0 ----
    float sge = 0.f, sgt = 0.f;
    while (bmask) {
        const int m = __builtin_ctz(bmask);
        bmask &= bmask - 1;
        const int qi = qoff + m;
        const int jq = jq0 + 128 * qi;
        float4 BX = *(const float4*)&tbx[4 * qi];
        float4 BY = *(const float4*)&tby[4 * qi];
        float4 C  = *(const float4*)&tbc[4 * qi];
#pragma unroll
        for (int k = 0; k < 2; ++k) {
            const int row = r0 + k;
            float e0 = fmaf(ax2s[k], BX.x, fmaf(ay2s[k], BY.x, C.x + A0s[k]));
            float e1 = fmaf(ax2s[k], BX.y, fmaf(ay2s[k], BY.y, C.y + A0s[k]));
            float e2 = fmaf(ax2s[k], BX.z, fmaf(ay2s[k], BY.z, C.z + A0s[k]));
            float e3 = fmaf(ax2s[k], BX.w, fmaf(ay2s[k], BY.w, C.w + A0s[k]));
            float v0 = fexp2(e0), v1 = fexp2(e1);
            float v2 = fexp2(e2), v3 = fexp2(e3);
            sge += (jq + 0 >= row) ? v0 : 0.f;  sgt += (jq + 0 > row) ? v0 : 0.f;
            sge += (jq + 1 >= row) ? v1 : 0.f;  sgt += (jq + 1 > row) ? v1 : 0.f;
            sge += (jq + 2 >= row) ? v2 : 0.f;  sgt += (jq + 2 > row) ? v2 : 0.f;
            sge += (jq + 3 >= row) ? v3 : 0.f;  sgt += (jq + 3 > row) ? v3 : 0.f;
        }
    }

    v2f st0 = s00 + s01, st1 = s10 + s11;
    double result = wt * ((double)(st0.x + st0.y) + (double)(st1.x + st1.y));
    if (sym) result += (term ? wMM : wNN) * (double)(sge + sgt);

    // ---- block reduce (f64), publish to spread slots ----
    for (int off = 32; off; off >>= 1) result += __shfl_down(result, off);
    if ((tid & 63) == 0) wredd[tid >> 6] = result;
    __syncthreads();
    if (tid == 0) {
        double s = wredd[0] + wredd[1] + wredd[2] + wredd[3];
        atomicAdd(&slots[t & 63], s);
    }
}

// ---------------- final: reduce 64 slots ----------------
__global__ void final_kernel(const double* __restrict__ slots,
                             float* __restrict__ out)
{
    const int tid = threadIdx.x;
    double s = slots[tid];
    for (int off = 32; off; off >>= 1) s += __shfl_down(s, off);
    if (tid == 0) out[0] = (float)s;
}

extern "C" void kernel_launch(void* const* d_in, const int* in_sizes, int n_in,
                              void* d_out, int out_size, void* d_ws, size_t ws_size,
                              hipStream_t stream)
{
    const float* base      = (const float*)d_in[0];
    const float* target    = (const float*)d_in[1];
    const float* log_sigma = (const float*)d_in[2];
    const float* log_scale = (const float*)d_in[3];
    float* out = (float*)d_out;

    int N = in_sizes[0] / 2;
    int M = in_sizes[1] / 2;

    char* ws = (char*)d_ws;
    double* msum  = (double*)ws;                 // 4 doubles
    double* slots = (double*)(ws + 64);          // 64 doubles
    float*  arr   = (float*)(ws + 1024);
    float* xsB = arr;
    float* ysB = xsB + N;
    float* csB = ysB + N;
    float* xsT = csB + N;
    float* ysT = xsT + M;
    float* csT = ysT + M;

    sort_kernel<<<2, 1024, 0, stream>>>(base, target, log_sigma, log_scale,
                                        N, M, xsB, ysB, csB, xsT, ysT, csT,
                                        msum, slots);
    mmd_main<<<NT_TOT, BLOCK, 0, stream>>>(N, M, xsB, ysB, csB,
                                           xsT, ysT, csT, msum, slots);
    final_kernel<<<1, 64, 0, stream>>>(slots, out);
}